// Round 11
// baseline (555.399 us; speedup 1.0000x reference)
//
#include <hip/hip_runtime.h>
#include <hip/hip_bf16.h>
#include <math.h>

#define B_SZ 4
#define SEQ  1024
#define DM   1024
#define DI   2048
#define DTR  64
#define DS   16
#define NTOK (B_SZ*SEQ)   /* 4096 tokens */
#define CHUNKS 16
#define CLEN   64         /* SEQ / CHUNKS */

typedef __hip_bfloat16 bf16;
typedef short bf16x8 __attribute__((ext_vector_type(8)));
typedef float f32x4  __attribute__((ext_vector_type(4)));
typedef unsigned int u32;

__device__ __forceinline__ float silu_f(float x) { return x / (1.f + __expf(-x)); }
__device__ __forceinline__ float softplus_f(float x) {
    return fmaxf(x, 0.f) + __logf(1.f + __expf(-fabsf(x)));
}
// raw v_exp_f32: safe for x<=0 (scan decay always satisfies this)
__device__ __forceinline__ float fexp2(float x) { return __builtin_amdgcn_exp2f(x); }
__device__ __forceinline__ void stv(float* p, float v) { *p = v; }
__device__ __forceinline__ void stv(bf16* p, float v)  { *p = __float2bfloat16(v); }
__device__ __forceinline__ unsigned short bfbits(float f) {
    union { bf16 h; unsigned short u; } c; c.h = __float2bfloat16(f); return c.u;
}
__device__ __forceinline__ float bf2f(short s) {
    union { float f; unsigned u; } c; c.u = ((unsigned)(unsigned short)s) << 16; return c.f;
}
// async 16B/lane global->LDS DMA; LDS dest = wave-uniform base + lane*16
__device__ __forceinline__ void async_cp16(const void* g, void* l) {
    __builtin_amdgcn_global_load_lds((const __attribute__((address_space(1))) u32*)g,
                                     (__attribute__((address_space(3))) u32*)l, 16, 0, 0);
}

// -------- prep: 7 plain cvt segs + 2 transpose-cvt segs (y==7/8) + LayerNorm (y==9) --
struct CvtSeg { const float* s; bf16* d; int n; };
struct CvtArgs { CvtSeg seg[7]; const float* tsrc[2]; bf16* tdst[2]; };
__global__ __launch_bounds__(256) void prep_kernel(CvtArgs a,
                                                   const float* __restrict__ x,
                                                   const float* __restrict__ g,
                                                   const float* __restrict__ be,
                                                   bf16* __restrict__ xn) {
    if (blockIdx.y < 7) {
        CvtSeg sg = a.seg[blockIdx.y];
        int base = (blockIdx.x * 256 + threadIdx.x) * 4;
        if (base >= sg.n) return;
        float4 v = *(const float4*)(sg.s + base);
        ushort4 o;
        o.x = bfbits(v.x); o.y = bfbits(v.y); o.z = bfbits(v.z); o.w = bfbits(v.w);
        *(ushort4*)(sg.d + base) = o;
        return;
    }
    if (blockIdx.y < 9) {
        // tiled transpose-cvt: (DM x DI) fp32 -> (DI x DM) bf16, 64x64 tiles
        if (blockIdx.x >= (DM / 64) * (DI / 64)) return;
        const float* src = a.tsrc[blockIdx.y - 7];
        bf16* dst = a.tdst[blockIdx.y - 7];
        int tr = blockIdx.x >> 5;      // row tile 0..15 (DM/64)
        int tc = blockIdx.x & 31;      // col tile 0..31 (DI/64)
        __shared__ short ts[64][72];
        int t = threadIdx.x;
#pragma unroll
        for (int p = 0; p < 4; ++p) {
            int r = p * 16 + (t >> 4);
            int c = (t & 15) * 4;
            float4 v = *(const float4*)(src + (long)(tr * 64 + r) * DI + tc * 64 + c);
            ts[r][c + 0] = (short)bfbits(v.x);
            ts[r][c + 1] = (short)bfbits(v.y);
            ts[r][c + 2] = (short)bfbits(v.z);
            ts[r][c + 3] = (short)bfbits(v.w);
        }
        __syncthreads();
#pragma unroll
        for (int p = 0; p < 4; ++p) {
            int k2 = p * 16 + (t >> 4);   // transposed row within tile
            int j  = (t & 15) * 4;        // transposed col within tile
            ushort4 o;
            o.x = (unsigned short)ts[j + 0][k2];
            o.y = (unsigned short)ts[j + 1][k2];
            o.z = (unsigned short)ts[j + 2][k2];
            o.w = (unsigned short)ts[j + 3][k2];
            *(ushort4*)(dst + (long)(tc * 64 + k2) * DM + tr * 64 + j) = o;
        }
        return;
    }
    // LayerNorm over last dim (1024), bf16 out
    int row = blockIdx.x;
    const float* xr = x + (long)row * DM;
    float v[4];
    float s = 0.f, ss = 0.f;
#pragma unroll
    for (int i = 0; i < 4; ++i) {
        v[i] = xr[threadIdx.x + 256 * i];
        s += v[i]; ss += v[i] * v[i];
    }
#pragma unroll
    for (int off = 32; off >= 1; off >>= 1) {
        s  += __shfl_xor(s, off, 64);
        ss += __shfl_xor(ss, off, 64);
    }
    __shared__ float sh[8];
    int wid = threadIdx.x >> 6;
    if ((threadIdx.x & 63) == 0) { sh[wid] = s; sh[4 + wid] = ss; }
    __syncthreads();
    s  = sh[0] + sh[1] + sh[2] + sh[3];
    ss = sh[4] + sh[5] + sh[6] + sh[7];
    float mu  = s / DM;
    float var = ss / DM - mu * mu;
    float rs  = rsqrtf(var + 1e-5f);
    bf16* xo = xn + (long)row * DM;
#pragma unroll
    for (int i = 0; i < 4; ++i) {
        int c = threadIdx.x + 256 * i;
        xo[c] = __float2bfloat16((v[i] - mu) * rs * g[c] + be[c]);
    }
}

// ---------------- bf16 MFMA GEMM: BK=64, global_load_lds, 8-way XOR swizzle ---------
struct GPtr { const bf16* A; const bf16* B; void* C; void* X; };
struct GB8 { GPtr p[8]; };

// EPI: 0 plain store; 2 softplus(acc + X[col]); 3 +bias+resid;
//      7 fp32 unsafeAtomicAdd into C (bias/resid only when blockIdx.z==0)
template <int EPI, typename OutT>
__global__ __launch_bounds__(256) void gemm_mfma(GB8 gb, int lda, int ldb, int ldc,
                                                 int N, int K,
                                                 const float* __restrict__ bias,
                                                 const float* __restrict__ resid, int ldr) {
    __shared__ __align__(16) short As[128 * 64];   // 16 KB
    __shared__ __align__(16) short Bs[128 * 64];   // 16 KB
    GPtr g = gb.p[blockIdx.z];
    const short* A = (const short*)g.A;
    const short* B = (const short*)g.B;
    OutT* C = (OutT*)g.C;
    const int tid = threadIdx.x;
    const int m0 = blockIdx.x * 128, n0 = blockIdx.y * 128;
    const int lane = tid & 63, wv = tid >> 6;
    const int wm = (wv >> 1) * 64, wn = (wv & 1) * 64;
    const int rsub = lane >> 3;
    const int sq   = ((lane & 7) ^ (rsub & 7)) * 8;   // swizzled 16B chunk (bf16 units)
    const short* pa[4];
    const short* pb[4];
    short* la[4];
    short* lb[4];
#pragma unroll
    for (int i = 0; i < 4; ++i) {
        int srow = wv * 32 + i * 8 + rsub;
        pa[i] = A + (long)(m0 + srow) * lda + sq;
        int rb = n0 + srow; rb = rb < N ? rb : N - 1;
        pb[i] = B + (long)rb * ldb + sq;
        la[i] = &As[(wv * 32 + i * 8) * 64];
        lb[i] = &Bs[(wv * 32 + i * 8) * 64];
    }
    f32x4 acc[4][4];
#pragma unroll
    for (int i = 0; i < 4; ++i)
#pragma unroll
        for (int j = 0; j < 4; ++j) acc[i][j] = (f32x4){0.f, 0.f, 0.f, 0.f};

    for (int k0 = 0; k0 < K; k0 += 64) {
        __syncthreads();
#pragma unroll
        for (int i = 0; i < 4; ++i) {
            async_cp16(pa[i] + k0, la[i]);
            async_cp16(pb[i] + k0, lb[i]);
        }
        __syncthreads();
#pragma unroll
        for (int h = 0; h < 2; ++h) {
            bf16x8 af[4], bfr[4];
#pragma unroll
            for (int t = 0; t < 4; ++t) {
                int ra = wm + t * 16 + (lane & 15);
                int ca = h * 4 + (lane >> 4);
                af[t]  = *(const bf16x8*)&As[ra * 64 + (ca ^ (ra & 7)) * 8];
                int rb = wn + t * 16 + (lane & 15);
                int cb = h * 4 + (lane >> 4);
                bfr[t] = *(const bf16x8*)&Bs[rb * 64 + (cb ^ (rb & 7)) * 8];
            }
#pragma unroll
            for (int i = 0; i < 4; ++i)
#pragma unroll
                for (int j = 0; j < 4; ++j)
                    acc[i][j] = __builtin_amdgcn_mfma_f32_16x16x32_bf16(af[i], bfr[j], acc[i][j], 0, 0, 0);
        }
    }
    float bcol[4] = {0.f, 0.f, 0.f, 0.f};
    bool wantb = (EPI == 2) || (EPI == 3) || (EPI == 7 && bias && blockIdx.z == 0);
    if (wantb) {
#pragma unroll
        for (int j = 0; j < 4; ++j) {
            int col = n0 + wn + j * 16 + (lane & 15);
            const float* bp = (EPI == 2) ? (const float*)g.X : bias;
            bcol[j] = (col < N) ? bp[col] : 0.f;
        }
    }
#pragma unroll
    for (int i = 0; i < 4; ++i) {
        int rowb = m0 + wm + i * 16 + ((lane >> 4) << 2);
#pragma unroll
        for (int j = 0; j < 4; ++j) {
            int col = n0 + wn + j * 16 + (lane & 15);
            if (col < N) {
#pragma unroll
                for (int rr = 0; rr < 4; ++rr) {
                    float v = acc[i][j][rr];
                    if (EPI == 3) v += bcol[j] + resid[(long)(rowb + rr) * ldr + col];
                    if (EPI == 2) v = softplus_f(v + bcol[j]);
                    if (EPI == 7) {
                        if (blockIdx.z == 0) {
                            if (bias)  v += bcol[j];
                            if (resid) v += resid[(long)(rowb + rr) * ldr + col];
                        }
                        unsafeAtomicAdd(&((float*)C)[(long)(rowb + rr) * ldc + col], v);
                    } else {
                        stv(&C[(long)(rowb + rr) * ldc + col], v);
                    }
                }
            }
        }
    }
}

// ---------------- dbl[:, 0:64] fp32 -> bf16 dt (both dirs) ----------------
__global__ __launch_bounds__(256) void dtcvt_kernel(const float* __restrict__ dbl,
                                                    bf16* __restrict__ dt_f,
                                                    bf16* __restrict__ dt_b) {
    int gid = blockIdx.x * 256 + threadIdx.x;
    long i = (long)gid * 4;
    const long per = (long)NTOK * 64;
    int dir = i >= per;
    long j = dir ? i - per : i;
    int row = (int)(j >> 6), col = (int)(j & 63);
    f32x4 v = *(const f32x4*)(dbl + (dir ? (long)NTOK * 96 : 0) + (long)row * 96 + col);
    ushort4 o;
    o.x = bfbits(v[0]); o.y = bfbits(v[1]); o.z = bfbits(v[2]); o.w = bfbits(v[3]);
    *(ushort4*)((dir ? dt_b : dt_f) + (long)row * 64 + col) = o;
}

// ---------------- Depthwise causal conv (window 4) + SiLU, 8 channels/thread -------
__global__ __launch_bounds__(256) void conv_kernel(const bf16* __restrict__ xi_f,
                                                   const bf16* __restrict__ xi_b,
                                                   const float* __restrict__ wf,
                                                   const float* __restrict__ bfs,
                                                   const float* __restrict__ wb,
                                                   const float* __restrict__ bb,
                                                   bf16* __restrict__ xc_f,
                                                   bf16* __restrict__ xc_b) {
    long idx = (long)blockIdx.x * 256 + threadIdx.x;
    const long per = (long)NTOK * (DI / 8);
    int dir = idx >= per;
    long i  = dir ? idx - per : idx;
    int  d8 = (int)(i & 255) * 8;
    long tok = i >> 8;
    int  l  = (int)(tok & (SEQ - 1));
    const float* w    = dir ? wb : wf;
    const float* bias = dir ? bb : bfs;
    const bf16* xi = (dir ? xi_b : xi_f) + tok * DI + d8;
    float acc[8], wreg[8][4];
#pragma unroll
    for (int j = 0; j < 8; ++j) {
        acc[j] = bias[d8 + j];
        f32x4 wv = *(const f32x4*)(w + (d8 + j) * 4);
        wreg[j][0] = wv[0]; wreg[j][1] = wv[1]; wreg[j][2] = wv[2]; wreg[j][3] = wv[3];
    }
#pragma unroll
    for (int k = 0; k < 4; ++k) {
        int lp = dir ? (l + 3 - k) : (l - 3 + k);
        if (lp >= 0 && lp < SEQ) {
            bf16x8 v = *(const bf16x8*)(xi + (long)(lp - l) * DI);
#pragma unroll
            for (int j = 0; j < 8; ++j) acc[j] = fmaf(wreg[j][k], bf2f(v[j]), acc[j]);
        }
    }
    bf16x8 o;
#pragma unroll
    for (int j = 0; j < 8; ++j) o[j] = (short)bfbits(silu_f(acc[j]));
    *(bf16x8*)((dir ? xc_b : xc_f) + tok * DI + d8) = o;
}

// =========== Chunked selective scan: one lane owns one channel (16 states) ==========
__global__ __launch_bounds__(256) void scan_reduce(
        const bf16* __restrict__ delta_f, const bf16* __restrict__ delta_b,
        const bf16* __restrict__ xc_f, const bf16* __restrict__ xc_b,
        const float* __restrict__ dbl_f, const float* __restrict__ dbl_b,
        const float* __restrict__ Alog_f, const float* __restrict__ Alog_b,
        float* __restrict__ red_a, float* __restrict__ red_b) {
    int blk = blockIdx.x;
    int dg  = blk & 7;
    int c   = (blk >> 3) & 15;
    int b   = (blk >> 7) & 3;
    int dir = blk >> 9;
    int d   = dg * 256 + threadIdx.x;
    const bf16* delta = dir ? delta_b : delta_f;
    const bf16* xc    = dir ? xc_b : xc_f;
    const float* dbl  = dir ? dbl_b : dbl_f;
    const float* Alog = (dir ? Alog_b : Alog_f) + d * DS;
    __shared__ float Bsh[CLEN * 16];
    {
        int r = threadIdx.x >> 2, q = threadIdx.x & 3;
        long grow = (long)b * SEQ + (dir ? (SEQ - 1 - c * CLEN - r) : (c * CLEN + r));
        *(f32x4*)&Bsh[r * 16 + q * 4] = *(const f32x4*)(dbl + grow * 96 + 64 + q * 4);
    }
    __syncthreads();
    float Ar2[DS], aprod[DS], bacc[DS];
#pragma unroll
    for (int j = 0; j < DS; ++j) {
        Ar2[j] = -__expf(Alog[j]) * 1.44269504089f;
        aprod[j] = 1.f; bacc[j] = 0.f;
    }
    long tstep = dir ? -1 : 1;
    long row = (long)b * SEQ + (dir ? SEQ - 1 - c * CLEN : c * CLEN);
    float dlt = __bfloat162float(delta[row * DI + d]);
    float u   = __bfloat162float(xc[row * DI + d]);
    for (int s = 0; s < CLEN; ++s) {
        long rown = row + tstep;
        float dltn = 0.f, un = 0.f;
        if (s + 1 < CLEN) {
            dltn = __bfloat162float(delta[rown * DI + d]);
            un   = __bfloat162float(xc[rown * DI + d]);
        }
        float du = dlt * u;
#pragma unroll
        for (int q = 0; q < 4; ++q) {
            f32x4 Bq = *(const f32x4*)&Bsh[s * 16 + q * 4];
#pragma unroll
            for (int j = 0; j < 4; ++j) {
                int ix = q * 4 + j;
                float dA = fexp2(dlt * Ar2[ix]);
                bacc[ix]  = fmaf(bacc[ix], dA, du * Bq[j]);
                aprod[ix] *= dA;
            }
        }
        row = rown; dlt = dltn; u = un;
    }
    long base = (((long)(dir * 4 + b) * CHUNKS + c) * DI + d) * 16;
#pragma unroll
    for (int q = 0; q < 4; ++q) {
        *(f32x4*)(red_a + base + q * 4) =
            (f32x4){aprod[q*4], aprod[q*4+1], aprod[q*4+2], aprod[q*4+3]};
        *(f32x4*)(red_b + base + q * 4) =
            (f32x4){bacc[q*4], bacc[q*4+1], bacc[q*4+2], bacc[q*4+3]};
    }
}

__global__ __launch_bounds__(256) void scan_combine(float* __restrict__ red_a,
                                                    const float* __restrict__ red_b) {
    int tid = blockIdx.x * 256 + threadIdx.x;
    int sub = tid & 3;
    int d   = (tid >> 2) & 2047;
    int db  = tid >> 13;
    f32x4 h = (f32x4){0.f, 0.f, 0.f, 0.f};
    for (int c = 0; c < CHUNKS; ++c) {
        long idx = (((long)db * CHUNKS + c) * DI + d) * 16 + sub * 4;
        f32x4 a = *(const f32x4*)(red_a + idx);
        f32x4 w = *(const f32x4*)(red_b + idx);
        *(f32x4*)(red_a + idx) = h;
#pragma unroll
        for (int j = 0; j < 4; ++j) h[j] = fmaf(a[j], h[j], w[j]);
    }
}

// writes gated y into PACKED buffer y[tok][dir*DI + d] (ld 2*DI) for the fused
// out-proj+fuse GEMM
__global__ __launch_bounds__(256) void scan_apply(
        const bf16* __restrict__ delta_f, const bf16* __restrict__ delta_b,
        const bf16* __restrict__ xc_f, const bf16* __restrict__ xc_b,
        const bf16* __restrict__ z_f, const bf16* __restrict__ z_b,
        const float* __restrict__ dbl_f, const float* __restrict__ dbl_b,
        const float* __restrict__ Alog_f, const float* __restrict__ Alog_b,
        const float* __restrict__ Df, const float* __restrict__ Db,
        const float* __restrict__ red_a, bf16* __restrict__ ypack) {
    int blk = blockIdx.x;
    int dg  = blk & 7;
    int c   = (blk >> 3) & 15;
    int b   = (blk >> 7) & 3;
    int dir = blk >> 9;
    int d   = dg * 256 + threadIdx.x;
    const bf16* delta = dir ? delta_b : delta_f;
    const bf16* xc    = dir ? xc_b : xc_f;
    const bf16* z     = dir ? z_b : z_f;
    const float* dbl  = dir ? dbl_b : dbl_f;
    const float* Alog = (dir ? Alog_b : Alog_f) + d * DS;
    float Dd = (dir ? Db : Df)[d];
    bf16* yo = ypack + dir * DI + d;
    __shared__ float BCsh[CLEN * 32];
#pragma unroll
    for (int it = 0; it < 2; ++it) {
        int i = it * 256 + threadIdx.x;
        int r = i >> 3, q = i & 7;
        long grow = (long)b * SEQ + (dir ? (SEQ - 1 - c * CLEN - r) : (c * CLEN + r));
        *(f32x4*)&BCsh[r * 32 + q * 4] = *(const f32x4*)(dbl + grow * 96 + 64 + q * 4);
    }
    __syncthreads();
    float Ar2[DS], h[DS];
#pragma unroll
    for (int j = 0; j < DS; ++j) Ar2[j] = -__expf(Alog[j]) * 1.44269504089f;
    {
        long base = (((long)(dir * 4 + b) * CHUNKS + c) * DI + d) * 16;
#pragma unroll
        for (int q = 0; q < 4; ++q) {
            f32x4 h0 = *(const f32x4*)(red_a + base + q * 4);
            h[q*4] = h0[0]; h[q*4+1] = h0[1]; h[q*4+2] = h0[2]; h[q*4+3] = h0[3];
        }
    }
    long tstep = dir ? -1 : 1;
    long row = (long)b * SEQ + (dir ? SEQ - 1 - c * CLEN : c * CLEN);
    float dlt = __bfloat162float(delta[row * DI + d]);
    float u   = __bfloat162float(xc[row * DI + d]);
    float zg  = __bfloat162float(z[row * DI + d]);
    for (int s = 0; s < CLEN; ++s) {
        long rown = row + tstep;
        float dltn = 0.f, un = 0.f, zgn = 0.f;
        if (s + 1 < CLEN) {
            dltn = __bfloat162float(delta[rown * DI + d]);
            un   = __bfloat162float(xc[rown * DI + d]);
            zgn  = __bfloat162float(z[rown * DI + d]);
        }
        float du = dlt * u;
        float y = 0.f;
#pragma unroll
        for (int q = 0; q < 4; ++q) {
            f32x4 Bq = *(const f32x4*)&BCsh[s * 32 + q * 4];
            f32x4 Cq = *(const f32x4*)&BCsh[s * 32 + 16 + q * 4];
#pragma unroll
            for (int j = 0; j < 4; ++j) {
                int ix = q * 4 + j;
                float dA = fexp2(dlt * Ar2[ix]);
                h[ix] = fmaf(h[ix], dA, du * Bq[j]);
                y = fmaf(h[ix], Cq[j], y);
            }
        }
        float yv = fmaf(u, Dd, y);
        yo[row * (2 * DI)] = __float2bfloat16(yv * silu_f(zg));
        row = rown; dlt = dltn; u = un; zg = zgn;
    }
}

extern "C" void kernel_launch(void* const* d_in, const int* in_sizes, int n_in,
                              void* d_out, int out_size, void* d_ws, size_t ws_size,
                              hipStream_t stream) {
    const float* x      = (const float*)d_in[0];
    const float* ln_g   = (const float*)d_in[1];
    const float* ln_b   = (const float*)d_in[2];
    const float* fus_w  = (const float*)d_in[3];
    const float* fus_b  = (const float*)d_in[4];
    const float* f_in_w = (const float*)d_in[5];
    const float* f_cw   = (const float*)d_in[6];
    const float* f_cb   = (const float*)d_in[7];
    const float* f_xpw  = (const float*)d_in[8];
    const float* f_dtw  = (const float*)d_in[9];
    const float* f_dtb  = (const float*)d_in[10];
    const float* f_Alog = (const float*)d_in[11];
    const float* f_D    = (const float*)d_in[12];
    const float* f_outw = (const float*)d_in[13];
    const float* b_in_w = (const float*)d_in[14];
    const float* b_cw   = (const float*)d_in[15];
    const float* b_cb   = (const float*)d_in[16];
    const float* b_xpw  = (const float*)d_in[17];
    const float* b_dtw  = (const float*)d_in[18];
    const float* b_dtb  = (const float*)d_in[19];
    const float* b_Alog = (const float*)d_in[20];
    const float* b_D    = (const float*)d_in[21];
    const float* b_outw = (const float*)d_in[22];
    float* out = (float*)d_out;

    char* w = (char*)d_ws;
    auto alloc = [&](size_t bytes) { char* p = w; w += (bytes + 255) & ~255UL; return p; };
    bf16* xn   = (bf16*)alloc((size_t)NTOK * DM * 2);
    bf16* xi_f = (bf16*)alloc((size_t)NTOK * DI * 2);
    bf16* xi_b = (bf16*)alloc((size_t)NTOK * DI * 2);
    bf16* z_f  = (bf16*)alloc((size_t)NTOK * DI * 2);
    bf16* z_b  = (bf16*)alloc((size_t)NTOK * DI * 2);
    bf16* xc_f = (bf16*)alloc((size_t)NTOK * DI * 2);
    bf16* xc_b = (bf16*)alloc((size_t)NTOK * DI * 2);
    bf16* ypack = (bf16*)alloc((size_t)NTOK * 2 * DI * 2);   // 32 MB packed y
    float* dbl = (float*)alloc((size_t)2 * NTOK * 96 * 4);
    float* dbl_f = dbl;
    float* dbl_b = dbl + (size_t)NTOK * 96;
    bf16* dt_f  = (bf16*)alloc((size_t)NTOK * DTR * 2);
    bf16* dt_b  = (bf16*)alloc((size_t)NTOK * DTR * 2);
    bf16* w_fin  = (bf16*)alloc((size_t)2 * DI * DM * 2);
    bf16* w_bin  = (bf16*)alloc((size_t)2 * DI * DM * 2);
    bf16* w_foutT = (bf16*)alloc((size_t)DI * DM * 2);   // out_w^T (DI x DM)
    bf16* w_boutT = (bf16*)alloc((size_t)DI * DM * 2);
    bf16* w_fus  = (bf16*)alloc((size_t)DM * 2 * DM * 2);
    bf16* w_comb = (bf16*)alloc((size_t)DM * 2 * DI * 2);  // Wcomb (DM x 2*DI) = 8 MB
    bf16* w_fxp  = (bf16*)alloc((size_t)96 * DI * 2);
    bf16* w_bxp  = (bf16*)alloc((size_t)96 * DI * 2);
    bf16* w_fdt  = (bf16*)alloc((size_t)DI * DTR * 2);
    bf16* w_bdt  = (bf16*)alloc((size_t)DI * DTR * 2);
    float* red_a = (float*)alloc((size_t)8 * CHUNKS * DI * 16 * 4);
    float* red_b = (float*)alloc((size_t)8 * CHUNKS * DI * 16 * 4);
    bf16* delta_f = xi_f;      // alias: xi dead after conv
    bf16* delta_b = xi_b;

    // 0. zero atomic target (dbl only; out no longer atomic)
    hipMemsetAsync(dbl, 0, (size_t)2 * NTOK * 96 * 4, stream);

    // 1. weight cvt (+ out_w transposes) + LayerNorm (one launch)
    CvtArgs ca;
    ca.seg[0] = {f_in_w, w_fin,  2 * DI * DM};
    ca.seg[1] = {b_in_w, w_bin,  2 * DI * DM};
    ca.seg[2] = {fus_w,  w_fus,  DM * 2 * DM};
    ca.seg[3] = {f_xpw,  w_fxp,  96 * DI};
    ca.seg[4] = {b_xpw,  w_bxp,  96 * DI};
    ca.seg[5] = {f_dtw,  w_fdt,  DI * DTR};
    ca.seg[6] = {b_dtw,  w_bdt,  DI * DTR};
    ca.tsrc[0] = f_outw; ca.tdst[0] = w_foutT;
    ca.tsrc[1] = b_outw; ca.tdst[1] = w_boutT;
    prep_kernel<<<dim3(4096, 10), 256, 0, stream>>>(ca, x, ln_g, ln_b, xn);
    // 1b. Wcomb = [fus_L @ f_out_w | fus_R @ b_out_w]  (z=2, M=1024 N=2048 K=1024)
    {
        GB8 gb{};
        gb.p[0] = {w_fus,      w_foutT, w_comb,      nullptr};
        gb.p[1] = {w_fus + DM, w_boutT, w_comb + DI, nullptr};
        gemm_mfma<0, bf16><<<dim3(8, 16, 2), 256, 0, stream>>>(gb, 2 * DM, DM, 2 * DI,
                                                               DI, DM, nullptr, nullptr, 0);
    }
    // 2. in-proj (batched z=4)
    {
        GB8 gb{};
        gb.p[0] = {xn, w_fin,                   xi_f, nullptr};
        gb.p[1] = {xn, w_fin + (size_t)DI * DM, z_f,  nullptr};
        gb.p[2] = {xn, w_bin,                   xi_b, nullptr};
        gb.p[3] = {xn, w_bin + (size_t)DI * DM, z_b,  nullptr};
        gemm_mfma<0, bf16><<<dim3(32, 16, 4), 256, 0, stream>>>(gb, DM, DM, DI, DI, DM,
                                                                nullptr, nullptr, 0);
    }
    // 3. depthwise conv + silu (8 ch/thread)
    conv_kernel<<<2 * NTOK, 256, 0, stream>>>(xi_f, xi_b, f_cw, f_cb,
                                              b_cw, b_cb, xc_f, xc_b);
    // 4. x-proj K-split x4 (z = dir*4 + slice), atomic fp32 into zeroed dbl
    {
        GB8 gb{};
        for (int s = 0; s < 4; ++s) {
            gb.p[s]     = {xc_f + s * 512, w_fxp + s * 512, dbl_f, nullptr};
            gb.p[4 + s] = {xc_b + s * 512, w_bxp + s * 512, dbl_b, nullptr};
        }
        gemm_mfma<7, float><<<dim3(32, 1, 8), 256, 0, stream>>>(gb, DI, DI, 96, 96, 512,
                                                                nullptr, nullptr, 0);
    }
    // 5. dt dup: dbl[:, 0:64] -> bf16
    dtcvt_kernel<<<512, 256, 0, stream>>>(dbl, dt_f, dt_b);
    // 6. dt-proj + softplus -> bf16 delta (MFMA, K=64, z=2)
    {
        GB8 gb{};
        gb.p[0] = {dt_f, w_fdt, delta_f, (void*)f_dtb};
        gb.p[1] = {dt_b, w_bdt, delta_b, (void*)b_dtb};
        gemm_mfma<2, bf16><<<dim3(32, 16, 2), 256, 0, stream>>>(gb, DTR, DTR, DI, DI, DTR,
                                                                nullptr, nullptr, 0);
    }
    // 7. chunked selective scan (3 passes); apply writes packed y
    scan_reduce<<<1024, 256, 0, stream>>>(delta_f, delta_b, xc_f, xc_b,
                                          dbl_f, dbl_b, f_Alog, b_Alog, red_a, red_b);
    scan_combine<<<256, 256, 0, stream>>>(red_a, red_b);
    scan_apply<<<1024, 256, 0, stream>>>(delta_f, delta_b, xc_f, xc_b, z_f, z_b,
                                         dbl_f, dbl_b, f_Alog, b_Alog, f_D, b_D,
                                         red_a, ypack);
    // 8. fused out-proj+fuse: out = ypack @ Wcomb^T + fus_b + x
    //    (M=4096, N=1024, K=4096)
    {
        GB8 gb{};
        gb.p[0] = {ypack, w_comb, out, nullptr};
        gemm_mfma<3, float><<<dim3(32, 8, 1), 256, 0, stream>>>(gb, 2 * DI, 2 * DI, DM,
                                                                DM, 2 * DI, fus_b, x, DM);
    }
}

// Round 12
// 550.727 us; speedup vs baseline: 1.0085x; 1.0085x over previous
//
#include <hip/hip_runtime.h>
#include <hip/hip_bf16.h>
#include <math.h>

#define B_SZ 4
#define SEQ  1024
#define DM   1024
#define DI   2048
#define DTR  64
#define DS   16
#define NTOK (B_SZ*SEQ)   /* 4096 tokens */
#define CHUNKS 16
#define CLEN   64         /* SEQ / CHUNKS */

typedef __hip_bfloat16 bf16;
typedef short bf16x8 __attribute__((ext_vector_type(8)));
typedef float f32x4  __attribute__((ext_vector_type(4)));
typedef unsigned int u32;

__device__ __forceinline__ float silu_f(float x) { return x / (1.f + __expf(-x)); }
__device__ __forceinline__ float softplus_f(float x) {
    return fmaxf(x, 0.f) + __logf(1.f + __expf(-fabsf(x)));
}
// raw v_exp_f32: safe for x<=0 (scan decay always satisfies this)
__device__ __forceinline__ float fexp2(float x) { return __builtin_amdgcn_exp2f(x); }
__device__ __forceinline__ void stv(float* p, float v) { *p = v; }
__device__ __forceinline__ void stv(bf16* p, float v)  { *p = __float2bfloat16(v); }
__device__ __forceinline__ unsigned short bfbits(float f) {
    union { bf16 h; unsigned short u; } c; c.h = __float2bfloat16(f); return c.u;
}
__device__ __forceinline__ float bf2f(short s) {
    union { float f; unsigned u; } c; c.u = ((unsigned)(unsigned short)s) << 16; return c.f;
}
// async 16B/lane global->LDS DMA; LDS dest = wave-uniform base + lane*16
__device__ __forceinline__ void async_cp16(const void* g, void* l) {
    __builtin_amdgcn_global_load_lds((const __attribute__((address_space(1))) u32*)g,
                                     (__attribute__((address_space(3))) u32*)l, 16, 0, 0);
}

// -------- prep: 7 plain cvt segs + 2 transpose-cvt segs (y==7/8) + LayerNorm (y==9) --
struct CvtSeg { const float* s; bf16* d; int n; };
struct CvtArgs { CvtSeg seg[7]; const float* tsrc[2]; bf16* tdst[2]; };
__global__ __launch_bounds__(256) void prep_kernel(CvtArgs a,
                                                   const float* __restrict__ x,
                                                   const float* __restrict__ g,
                                                   const float* __restrict__ be,
                                                   bf16* __restrict__ xn) {
    if (blockIdx.y < 7) {
        CvtSeg sg = a.seg[blockIdx.y];
        int base = (blockIdx.x * 256 + threadIdx.x) * 4;
        if (base >= sg.n) return;
        float4 v = *(const float4*)(sg.s + base);
        ushort4 o;
        o.x = bfbits(v.x); o.y = bfbits(v.y); o.z = bfbits(v.z); o.w = bfbits(v.w);
        *(ushort4*)(sg.d + base) = o;
        return;
    }
    if (blockIdx.y < 9) {
        // tiled transpose-cvt: (DM x DI) fp32 -> (DI x DM) bf16, 64x64 tiles
        if (blockIdx.x >= (DM / 64) * (DI / 64)) return;
        const float* src = a.tsrc[blockIdx.y - 7];
        bf16* dst = a.tdst[blockIdx.y - 7];
        int tr = blockIdx.x >> 5;      // row tile 0..15 (DM/64)
        int tc = blockIdx.x & 31;      // col tile 0..31 (DI/64)
        __shared__ short ts[64][72];
        int t = threadIdx.x;
#pragma unroll
        for (int p = 0; p < 4; ++p) {
            int r = p * 16 + (t >> 4);
            int c = (t & 15) * 4;
            float4 v = *(const float4*)(src + (long)(tr * 64 + r) * DI + tc * 64 + c);
            ts[r][c + 0] = (short)bfbits(v.x);
            ts[r][c + 1] = (short)bfbits(v.y);
            ts[r][c + 2] = (short)bfbits(v.z);
            ts[r][c + 3] = (short)bfbits(v.w);
        }
        __syncthreads();
#pragma unroll
        for (int p = 0; p < 4; ++p) {
            int k2 = p * 16 + (t >> 4);   // transposed row within tile
            int j  = (t & 15) * 4;        // transposed col within tile
            ushort4 o;
            o.x = (unsigned short)ts[j + 0][k2];
            o.y = (unsigned short)ts[j + 1][k2];
            o.z = (unsigned short)ts[j + 2][k2];
            o.w = (unsigned short)ts[j + 3][k2];
            *(ushort4*)(dst + (long)(tc * 64 + k2) * DM + tr * 64 + j) = o;
        }
        return;
    }
    // LayerNorm over last dim (1024), bf16 out
    int row = blockIdx.x;
    const float* xr = x + (long)row * DM;
    float v[4];
    float s = 0.f, ss = 0.f;
#pragma unroll
    for (int i = 0; i < 4; ++i) {
        v[i] = xr[threadIdx.x + 256 * i];
        s += v[i]; ss += v[i] * v[i];
    }
#pragma unroll
    for (int off = 32; off >= 1; off >>= 1) {
        s  += __shfl_xor(s, off, 64);
        ss += __shfl_xor(ss, off, 64);
    }
    __shared__ float sh[8];
    int wid = threadIdx.x >> 6;
    if ((threadIdx.x & 63) == 0) { sh[wid] = s; sh[4 + wid] = ss; }
    __syncthreads();
    s  = sh[0] + sh[1] + sh[2] + sh[3];
    ss = sh[4] + sh[5] + sh[6] + sh[7];
    float mu  = s / DM;
    float var = ss / DM - mu * mu;
    float rs  = rsqrtf(var + 1e-5f);
    bf16* xo = xn + (long)row * DM;
#pragma unroll
    for (int i = 0; i < 4; ++i) {
        int c = threadIdx.x + 256 * i;
        xo[c] = __float2bfloat16((v[i] - mu) * rs * g[c] + be[c]);
    }
}

// ---------------- bf16 MFMA GEMM: BK=64, global_load_lds, 8-way XOR swizzle ---------
struct GPtr { const bf16* A; const bf16* B; void* C; void* X; };
struct GB8 { GPtr p[8]; };

// EPI: 0 plain store; 2 softplus(acc + X[col]); 3 +bias+resid;
//      7 fp32 unsafeAtomicAdd into C (bias/resid only when blockIdx.z==0)
template <int EPI, typename OutT>
__global__ __launch_bounds__(256) void gemm_mfma(GB8 gb, int lda, int ldb, int ldc,
                                                 int N, int K,
                                                 const float* __restrict__ bias,
                                                 const float* __restrict__ resid, int ldr) {
    __shared__ __align__(16) short As[128 * 64];   // 16 KB
    __shared__ __align__(16) short Bs[128 * 64];   // 16 KB
    GPtr g = gb.p[blockIdx.z];
    const short* A = (const short*)g.A;
    const short* B = (const short*)g.B;
    OutT* C = (OutT*)g.C;
    const int tid = threadIdx.x;
    const int m0 = blockIdx.x * 128, n0 = blockIdx.y * 128;
    const int lane = tid & 63, wv = tid >> 6;
    const int wm = (wv >> 1) * 64, wn = (wv & 1) * 64;
    const int rsub = lane >> 3;
    const int sq   = ((lane & 7) ^ (rsub & 7)) * 8;   // swizzled 16B chunk (bf16 units)
    const short* pa[4];
    const short* pb[4];
    short* la[4];
    short* lb[4];
#pragma unroll
    for (int i = 0; i < 4; ++i) {
        int srow = wv * 32 + i * 8 + rsub;
        pa[i] = A + (long)(m0 + srow) * lda + sq;
        int rb = n0 + srow; rb = rb < N ? rb : N - 1;
        pb[i] = B + (long)rb * ldb + sq;
        la[i] = &As[(wv * 32 + i * 8) * 64];
        lb[i] = &Bs[(wv * 32 + i * 8) * 64];
    }
    f32x4 acc[4][4];
#pragma unroll
    for (int i = 0; i < 4; ++i)
#pragma unroll
        for (int j = 0; j < 4; ++j) acc[i][j] = (f32x4){0.f, 0.f, 0.f, 0.f};

    for (int k0 = 0; k0 < K; k0 += 64) {
        __syncthreads();
#pragma unroll
        for (int i = 0; i < 4; ++i) {
            async_cp16(pa[i] + k0, la[i]);
            async_cp16(pb[i] + k0, lb[i]);
        }
        __syncthreads();
#pragma unroll
        for (int h = 0; h < 2; ++h) {
            bf16x8 af[4], bfr[4];
#pragma unroll
            for (int t = 0; t < 4; ++t) {
                int ra = wm + t * 16 + (lane & 15);
                int ca = h * 4 + (lane >> 4);
                af[t]  = *(const bf16x8*)&As[ra * 64 + (ca ^ (ra & 7)) * 8];
                int rb = wn + t * 16 + (lane & 15);
                int cb = h * 4 + (lane >> 4);
                bfr[t] = *(const bf16x8*)&Bs[rb * 64 + (cb ^ (rb & 7)) * 8];
            }
#pragma unroll
            for (int i = 0; i < 4; ++i)
#pragma unroll
                for (int j = 0; j < 4; ++j)
                    acc[i][j] = __builtin_amdgcn_mfma_f32_16x16x32_bf16(af[i], bfr[j], acc[i][j], 0, 0, 0);
        }
    }
    float bcol[4] = {0.f, 0.f, 0.f, 0.f};
    bool wantb = (EPI == 2) || (EPI == 3) || (EPI == 7 && bias && blockIdx.z == 0);
    if (wantb) {
#pragma unroll
        for (int j = 0; j < 4; ++j) {
            int col = n0 + wn + j * 16 + (lane & 15);
            const float* bp = (EPI == 2) ? (const float*)g.X : bias;
            bcol[j] = (col < N) ? bp[col] : 0.f;
        }
    }
#pragma unroll
    for (int i = 0; i < 4; ++i) {
        int rowb = m0 + wm + i * 16 + ((lane >> 4) << 2);
#pragma unroll
        for (int j = 0; j < 4; ++j) {
            int col = n0 + wn + j * 16 + (lane & 15);
            if (col < N) {
#pragma unroll
                for (int rr = 0; rr < 4; ++rr) {
                    float v = acc[i][j][rr];
                    if (EPI == 3) v += bcol[j] + resid[(long)(rowb + rr) * ldr + col];
                    if (EPI == 2) v = softplus_f(v + bcol[j]);
                    if (EPI == 7) {
                        if (blockIdx.z == 0) {
                            if (bias)  v += bcol[j];
                            if (resid) v += resid[(long)(rowb + rr) * ldr + col];
                        }
                        unsafeAtomicAdd(&((float*)C)[(long)(rowb + rr) * ldc + col], v);
                    } else {
                        stv(&C[(long)(rowb + rr) * ldc + col], v);
                    }
                }
            }
        }
    }
}

// ---------------- dbl[:, 0:64] fp32 -> bf16 dt (both dirs) ----------------
__global__ __launch_bounds__(256) void dtcvt_kernel(const float* __restrict__ dbl,
                                                    bf16* __restrict__ dt_f,
                                                    bf16* __restrict__ dt_b) {
    int gid = blockIdx.x * 256 + threadIdx.x;
    long i = (long)gid * 4;
    const long per = (long)NTOK * 64;
    int dir = i >= per;
    long j = dir ? i - per : i;
    int row = (int)(j >> 6), col = (int)(j & 63);
    f32x4 v = *(const f32x4*)(dbl + (dir ? (long)NTOK * 96 : 0) + (long)row * 96 + col);
    ushort4 o;
    o.x = bfbits(v[0]); o.y = bfbits(v[1]); o.z = bfbits(v[2]); o.w = bfbits(v[3]);
    *(ushort4*)((dir ? dt_b : dt_f) + (long)row * 64 + col) = o;
}

// ---------------- Depthwise causal conv (window 4) + SiLU, 8 channels/thread -------
__global__ __launch_bounds__(256) void conv_kernel(const bf16* __restrict__ xi_f,
                                                   const bf16* __restrict__ xi_b,
                                                   const float* __restrict__ wf,
                                                   const float* __restrict__ bfs,
                                                   const float* __restrict__ wb,
                                                   const float* __restrict__ bb,
                                                   bf16* __restrict__ xc_f,
                                                   bf16* __restrict__ xc_b) {
    long idx = (long)blockIdx.x * 256 + threadIdx.x;
    const long per = (long)NTOK * (DI / 8);
    int dir = idx >= per;
    long i  = dir ? idx - per : idx;
    int  d8 = (int)(i & 255) * 8;
    long tok = i >> 8;
    int  l  = (int)(tok & (SEQ - 1));
    const float* w    = dir ? wb : wf;
    const float* bias = dir ? bb : bfs;
    const bf16* xi = (dir ? xi_b : xi_f) + tok * DI + d8;
    float acc[8], wreg[8][4];
#pragma unroll
    for (int j = 0; j < 8; ++j) {
        acc[j] = bias[d8 + j];
        f32x4 wv = *(const f32x4*)(w + (d8 + j) * 4);
        wreg[j][0] = wv[0]; wreg[j][1] = wv[1]; wreg[j][2] = wv[2]; wreg[j][3] = wv[3];
    }
#pragma unroll
    for (int k = 0; k < 4; ++k) {
        int lp = dir ? (l + 3 - k) : (l - 3 + k);
        if (lp >= 0 && lp < SEQ) {
            bf16x8 v = *(const bf16x8*)(xi + (long)(lp - l) * DI);
#pragma unroll
            for (int j = 0; j < 8; ++j) acc[j] = fmaf(wreg[j][k], bf2f(v[j]), acc[j]);
        }
    }
    bf16x8 o;
#pragma unroll
    for (int j = 0; j < 8; ++j) o[j] = (short)bfbits(silu_f(acc[j]));
    *(bf16x8*)((dir ? xc_b : xc_f) + tok * DI + d8) = o;
}

// =========== Chunked selective scan: one lane owns one channel (16 states) ==========
__global__ __launch_bounds__(256) void scan_reduce(
        const bf16* __restrict__ delta_f, const bf16* __restrict__ delta_b,
        const bf16* __restrict__ xc_f, const bf16* __restrict__ xc_b,
        const float* __restrict__ dbl_f, const float* __restrict__ dbl_b,
        const float* __restrict__ Alog_f, const float* __restrict__ Alog_b,
        float* __restrict__ red_a, float* __restrict__ red_b) {
    int blk = blockIdx.x;
    int dg  = blk & 7;
    int c   = (blk >> 3) & 15;
    int b   = (blk >> 7) & 3;
    int dir = blk >> 9;
    int d   = dg * 256 + threadIdx.x;
    const bf16* delta = dir ? delta_b : delta_f;
    const bf16* xc    = dir ? xc_b : xc_f;
    const float* dbl  = dir ? dbl_b : dbl_f;
    const float* Alog = (dir ? Alog_b : Alog_f) + d * DS;
    __shared__ float Bsh[CLEN * 16];
    {
        int r = threadIdx.x >> 2, q = threadIdx.x & 3;
        long grow = (long)b * SEQ + (dir ? (SEQ - 1 - c * CLEN - r) : (c * CLEN + r));
        *(f32x4*)&Bsh[r * 16 + q * 4] = *(const f32x4*)(dbl + grow * 96 + 64 + q * 4);
    }
    __syncthreads();
    float Ar2[DS], aprod[DS], bacc[DS];
#pragma unroll
    for (int j = 0; j < DS; ++j) {
        Ar2[j] = -__expf(Alog[j]) * 1.44269504089f;
        aprod[j] = 1.f; bacc[j] = 0.f;
    }
    long tstep = dir ? -1 : 1;
    long row = (long)b * SEQ + (dir ? SEQ - 1 - c * CLEN : c * CLEN);
    float dlt = __bfloat162float(delta[row * DI + d]);
    float u   = __bfloat162float(xc[row * DI + d]);
    for (int s = 0; s < CLEN; ++s) {
        long rown = row + tstep;
        float dltn = 0.f, un = 0.f;
        if (s + 1 < CLEN) {
            dltn = __bfloat162float(delta[rown * DI + d]);
            un   = __bfloat162float(xc[rown * DI + d]);
        }
        float du = dlt * u;
#pragma unroll
        for (int q = 0; q < 4; ++q) {
            f32x4 Bq = *(const f32x4*)&Bsh[s * 16 + q * 4];
#pragma unroll
            for (int j = 0; j < 4; ++j) {
                int ix = q * 4 + j;
                float dA = fexp2(dlt * Ar2[ix]);
                bacc[ix]  = fmaf(bacc[ix], dA, du * Bq[j]);
                aprod[ix] *= dA;
            }
        }
        row = rown; dlt = dltn; u = un;
    }
    long base = (((long)(dir * 4 + b) * CHUNKS + c) * DI + d) * 16;
#pragma unroll
    for (int q = 0; q < 4; ++q) {
        *(f32x4*)(red_a + base + q * 4) =
            (f32x4){aprod[q*4], aprod[q*4+1], aprod[q*4+2], aprod[q*4+3]};
        *(f32x4*)(red_b + base + q * 4) =
            (f32x4){bacc[q*4], bacc[q*4+1], bacc[q*4+2], bacc[q*4+3]};
    }
}

__global__ __launch_bounds__(256) void scan_combine(float* __restrict__ red_a,
                                                    const float* __restrict__ red_b) {
    int tid = blockIdx.x * 256 + threadIdx.x;
    int sub = tid & 3;
    int d   = (tid >> 2) & 2047;
    int db  = tid >> 13;
    f32x4 h = (f32x4){0.f, 0.f, 0.f, 0.f};
    for (int c = 0; c < CHUNKS; ++c) {
        long idx = (((long)db * CHUNKS + c) * DI + d) * 16 + sub * 4;
        f32x4 a = *(const f32x4*)(red_a + idx);
        f32x4 w = *(const f32x4*)(red_b + idx);
        *(f32x4*)(red_a + idx) = h;
#pragma unroll
        for (int j = 0; j < 4; ++j) h[j] = fmaf(a[j], h[j], w[j]);
    }
}

// writes gated y into PACKED buffer y[tok][dir*DI + d] (ld 2*DI)
__global__ __launch_bounds__(256) void scan_apply(
        const bf16* __restrict__ delta_f, const bf16* __restrict__ delta_b,
        const bf16* __restrict__ xc_f, const bf16* __restrict__ xc_b,
        const bf16* __restrict__ z_f, const bf16* __restrict__ z_b,
        const float* __restrict__ dbl_f, const float* __restrict__ dbl_b,
        const float* __restrict__ Alog_f, const float* __restrict__ Alog_b,
        const float* __restrict__ Df, const float* __restrict__ Db,
        const float* __restrict__ red_a, bf16* __restrict__ ypack) {
    int blk = blockIdx.x;
    int dg  = blk & 7;
    int c   = (blk >> 3) & 15;
    int b   = (blk >> 7) & 3;
    int dir = blk >> 9;
    int d   = dg * 256 + threadIdx.x;
    const bf16* delta = dir ? delta_b : delta_f;
    const bf16* xc    = dir ? xc_b : xc_f;
    const bf16* z     = dir ? z_b : z_f;
    const float* dbl  = dir ? dbl_b : dbl_f;
    const float* Alog = (dir ? Alog_b : Alog_f) + d * DS;
    float Dd = (dir ? Db : Df)[d];
    bf16* yo = ypack + dir * DI + d;
    __shared__ float BCsh[CLEN * 32];
#pragma unroll
    for (int it = 0; it < 2; ++it) {
        int i = it * 256 + threadIdx.x;
        int r = i >> 3, q = i & 7;
        long grow = (long)b * SEQ + (dir ? (SEQ - 1 - c * CLEN - r) : (c * CLEN + r));
        *(f32x4*)&BCsh[r * 32 + q * 4] = *(const f32x4*)(dbl + grow * 96 + 64 + q * 4);
    }
    __syncthreads();
    float Ar2[DS], h[DS];
#pragma unroll
    for (int j = 0; j < DS; ++j) Ar2[j] = -__expf(Alog[j]) * 1.44269504089f;
    {
        long base = (((long)(dir * 4 + b) * CHUNKS + c) * DI + d) * 16;
#pragma unroll
        for (int q = 0; q < 4; ++q) {
            f32x4 h0 = *(const f32x4*)(red_a + base + q * 4);
            h[q*4] = h0[0]; h[q*4+1] = h0[1]; h[q*4+2] = h0[2]; h[q*4+3] = h0[3];
        }
    }
    long tstep = dir ? -1 : 1;
    long row = (long)b * SEQ + (dir ? SEQ - 1 - c * CLEN : c * CLEN);
    float dlt = __bfloat162float(delta[row * DI + d]);
    float u   = __bfloat162float(xc[row * DI + d]);
    float zg  = __bfloat162float(z[row * DI + d]);
    for (int s = 0; s < CLEN; ++s) {
        long rown = row + tstep;
        float dltn = 0.f, un = 0.f, zgn = 0.f;
        if (s + 1 < CLEN) {
            dltn = __bfloat162float(delta[rown * DI + d]);
            un   = __bfloat162float(xc[rown * DI + d]);
            zgn  = __bfloat162float(z[rown * DI + d]);
        }
        float du = dlt * u;
        float y = 0.f;
#pragma unroll
        for (int q = 0; q < 4; ++q) {
            f32x4 Bq = *(const f32x4*)&BCsh[s * 32 + q * 4];
            f32x4 Cq = *(const f32x4*)&BCsh[s * 32 + 16 + q * 4];
#pragma unroll
            for (int j = 0; j < 4; ++j) {
                int ix = q * 4 + j;
                float dA = fexp2(dlt * Ar2[ix]);
                h[ix] = fmaf(h[ix], dA, du * Bq[j]);
                y = fmaf(h[ix], Cq[j], y);
            }
        }
        float yv = fmaf(u, Dd, y);
        yo[row * (2 * DI)] = __float2bfloat16(yv * silu_f(zg));
        row = rown; dlt = dltn; u = un; zg = zgn;
    }
}

extern "C" void kernel_launch(void* const* d_in, const int* in_sizes, int n_in,
                              void* d_out, int out_size, void* d_ws, size_t ws_size,
                              hipStream_t stream) {
    const float* x      = (const float*)d_in[0];
    const float* ln_g   = (const float*)d_in[1];
    const float* ln_b   = (const float*)d_in[2];
    const float* fus_w  = (const float*)d_in[3];
    const float* fus_b  = (const float*)d_in[4];
    const float* f_in_w = (const float*)d_in[5];
    const float* f_cw   = (const float*)d_in[6];
    const float* f_cb   = (const float*)d_in[7];
    const float* f_xpw  = (const float*)d_in[8];
    const float* f_dtw  = (const float*)d_in[9];
    const float* f_dtb  = (const float*)d_in[10];
    const float* f_Alog = (const float*)d_in[11];
    const float* f_D    = (const float*)d_in[12];
    const float* f_outw = (const float*)d_in[13];
    const float* b_in_w = (const float*)d_in[14];
    const float* b_cw   = (const float*)d_in[15];
    const float* b_cb   = (const float*)d_in[16];
    const float* b_xpw  = (const float*)d_in[17];
    const float* b_dtw  = (const float*)d_in[18];
    const float* b_dtb  = (const float*)d_in[19];
    const float* b_Alog = (const float*)d_in[20];
    const float* b_D    = (const float*)d_in[21];
    const float* b_outw = (const float*)d_in[22];
    float* out = (float*)d_out;

    char* w = (char*)d_ws;
    auto alloc = [&](size_t bytes) { char* p = w; w += (bytes + 255) & ~255UL; return p; };
    bf16* xn   = (bf16*)alloc((size_t)NTOK * DM * 2);
    bf16* xi_f = (bf16*)alloc((size_t)NTOK * DI * 2);
    bf16* xi_b = (bf16*)alloc((size_t)NTOK * DI * 2);
    bf16* z_f  = (bf16*)alloc((size_t)NTOK * DI * 2);
    bf16* z_b  = (bf16*)alloc((size_t)NTOK * DI * 2);
    bf16* xc_f = (bf16*)alloc((size_t)NTOK * DI * 2);
    bf16* xc_b = (bf16*)alloc((size_t)NTOK * DI * 2);
    bf16* ypack = (bf16*)alloc((size_t)NTOK * 2 * DI * 2);   // 32 MB packed y
    float* dbl = (float*)alloc((size_t)2 * NTOK * 96 * 4);
    float* dbl_f = dbl;
    float* dbl_b = dbl + (size_t)NTOK * 96;
    bf16* dt_f  = (bf16*)alloc((size_t)NTOK * DTR * 2);
    bf16* dt_b  = (bf16*)alloc((size_t)NTOK * DTR * 2);
    bf16* w_fin  = (bf16*)alloc((size_t)2 * DI * DM * 2);
    bf16* w_bin  = (bf16*)alloc((size_t)2 * DI * DM * 2);
    bf16* w_foutT = (bf16*)alloc((size_t)DI * DM * 2);   // out_w^T (DI x DM)
    bf16* w_boutT = (bf16*)alloc((size_t)DI * DM * 2);
    bf16* w_fus  = (bf16*)alloc((size_t)DM * 2 * DM * 2);
    bf16* w_comb = (bf16*)alloc((size_t)DM * 2 * DI * 2);  // Wcomb (DM x 2*DI) = 8 MB
    bf16* w_fxp  = (bf16*)alloc((size_t)96 * DI * 2);
    bf16* w_bxp  = (bf16*)alloc((size_t)96 * DI * 2);
    bf16* w_fdt  = (bf16*)alloc((size_t)DI * DTR * 2);
    bf16* w_bdt  = (bf16*)alloc((size_t)DI * DTR * 2);
    float* red_a = (float*)alloc((size_t)8 * CHUNKS * DI * 16 * 4);
    float* red_b = (float*)alloc((size_t)8 * CHUNKS * DI * 16 * 4);
    bf16* delta_f = xi_f;      // alias: xi dead after conv
    bf16* delta_b = xi_b;

    // 0. zero atomic targets
    hipMemsetAsync(dbl, 0, (size_t)2 * NTOK * 96 * 4, stream);
    hipMemsetAsync(out, 0, (size_t)NTOK * DM * 4, stream);

    // 1. weight cvt (+ out_w transposes) + LayerNorm (one launch)
    CvtArgs ca;
    ca.seg[0] = {f_in_w, w_fin,  2 * DI * DM};
    ca.seg[1] = {b_in_w, w_bin,  2 * DI * DM};
    ca.seg[2] = {fus_w,  w_fus,  DM * 2 * DM};
    ca.seg[3] = {f_xpw,  w_fxp,  96 * DI};
    ca.seg[4] = {b_xpw,  w_bxp,  96 * DI};
    ca.seg[5] = {f_dtw,  w_fdt,  DI * DTR};
    ca.seg[6] = {b_dtw,  w_bdt,  DI * DTR};
    ca.tsrc[0] = f_outw; ca.tdst[0] = w_foutT;
    ca.tsrc[1] = b_outw; ca.tdst[1] = w_boutT;
    prep_kernel<<<dim3(4096, 10), 256, 0, stream>>>(ca, x, ln_g, ln_b, xn);
    // 1b. Wcomb = [fus_L @ f_out_w | fus_R @ b_out_w]  (z=2, M=1024 N=2048 K=1024)
    {
        GB8 gb{};
        gb.p[0] = {w_fus,      w_foutT, w_comb,      nullptr};
        gb.p[1] = {w_fus + DM, w_boutT, w_comb + DI, nullptr};
        gemm_mfma<0, bf16><<<dim3(8, 16, 2), 256, 0, stream>>>(gb, 2 * DM, DM, 2 * DI,
                                                               DI, DM, nullptr, nullptr, 0);
    }
    // 2. in-proj (batched z=4)
    {
        GB8 gb{};
        gb.p[0] = {xn, w_fin,                   xi_f, nullptr};
        gb.p[1] = {xn, w_fin + (size_t)DI * DM, z_f,  nullptr};
        gb.p[2] = {xn, w_bin,                   xi_b, nullptr};
        gb.p[3] = {xn, w_bin + (size_t)DI * DM, z_b,  nullptr};
        gemm_mfma<0, bf16><<<dim3(32, 16, 4), 256, 0, stream>>>(gb, DM, DM, DI, DI, DM,
                                                                nullptr, nullptr, 0);
    }
    // 3. depthwise conv + silu (8 ch/thread)
    conv_kernel<<<2 * NTOK, 256, 0, stream>>>(xi_f, xi_b, f_cw, f_cb,
                                              b_cw, b_cb, xc_f, xc_b);
    // 4. x-proj K-split x4 (z = dir*4 + slice), atomic fp32 into zeroed dbl
    {
        GB8 gb{};
        for (int s = 0; s < 4; ++s) {
            gb.p[s]     = {xc_f + s * 512, w_fxp + s * 512, dbl_f, nullptr};
            gb.p[4 + s] = {xc_b + s * 512, w_bxp + s * 512, dbl_b, nullptr};
        }
        gemm_mfma<7, float><<<dim3(32, 1, 8), 256, 0, stream>>>(gb, DI, DI, 96, 96, 512,
                                                                nullptr, nullptr, 0);
    }
    // 5. dt dup: dbl[:, 0:64] -> bf16
    dtcvt_kernel<<<512, 256, 0, stream>>>(dbl, dt_f, dt_b);
    // 6. dt-proj + softplus -> bf16 delta (MFMA, K=64, z=2)
    {
        GB8 gb{};
        gb.p[0] = {dt_f, w_fdt, delta_f, (void*)f_dtb};
        gb.p[1] = {dt_b, w_bdt, delta_b, (void*)b_dtb};
        gemm_mfma<2, bf16><<<dim3(32, 16, 2), 256, 0, stream>>>(gb, DTR, DTR, DI, DI, DTR,
                                                                nullptr, nullptr, 0);
    }
    // 7. chunked selective scan (3 passes); apply writes packed y
    scan_reduce<<<1024, 256, 0, stream>>>(delta_f, delta_b, xc_f, xc_b,
                                          dbl_f, dbl_b, f_Alog, b_Alog, red_a, red_b);
    scan_combine<<<256, 256, 0, stream>>>(red_a, red_b);
    scan_apply<<<1024, 256, 0, stream>>>(delta_f, delta_b, xc_f, xc_b, z_f, z_b,
                                         dbl_f, dbl_b, f_Alog, b_Alog, f_D, b_D,
                                         red_a, ypack);
    // 8. fused out-proj+fuse, K-split x2 (z = slice), atomic into zeroed out;
    //    bias+resid applied by slice 0. (M=4096, N=1024, K=2048/slice)
    {
        GB8 gb{};
        gb.p[0] = {ypack,      w_comb,      out, nullptr};
        gb.p[1] = {ypack + DI, w_comb + DI, out, nullptr};
        gemm_mfma<7, float><<<dim3(32, 8, 2), 256, 0, stream>>>(gb, 2 * DI, 2 * DI, DM,
                                                                DM, DI, fus_b, x, DM);
    }
}

// Round 13
// 497.538 us; speedup vs baseline: 1.1163x; 1.1069x over previous
//
#include <hip/hip_runtime.h>
#include <hip/hip_bf16.h>
#include <math.h>

#define B_SZ 4
#define SEQ  1024
#define DM   1024
#define DI   2048
#define DTR  64
#define DS   16
#define NTOK (B_SZ*SEQ)   /* 4096 tokens */
#define CHUNKS 16
#define CLEN   64         /* SEQ / CHUNKS */

typedef __hip_bfloat16 bf16;
typedef short bf16x8 __attribute__((ext_vector_type(8)));
typedef float f32x4  __attribute__((ext_vector_type(4)));
typedef unsigned int u32;

__device__ __forceinline__ float silu_f(float x) { return x / (1.f + __expf(-x)); }
__device__ __forceinline__ float softplus_f(float x) {
    return fmaxf(x, 0.f) + __logf(1.f + __expf(-fabsf(x)));
}
// raw v_exp_f32: safe for x<=0 (scan decay always satisfies this)
__device__ __forceinline__ float fexp2(float x) { return __builtin_amdgcn_exp2f(x); }
__device__ __forceinline__ void stv(float* p, float v) { *p = v; }
__device__ __forceinline__ void stv(bf16* p, float v)  { *p = __float2bfloat16(v); }
__device__ __forceinline__ unsigned short bfbits(float f) {
    union { bf16 h; unsigned short u; } c; c.h = __float2bfloat16(f); return c.u;
}
__device__ __forceinline__ float bf2f(short s) {
    union { float f; unsigned u; } c; c.u = ((unsigned)(unsigned short)s) << 16; return c.f;
}
// async 16B/lane global->LDS DMA; LDS dest = wave-uniform base + lane*16
__device__ __forceinline__ void async_cp16(const void* g, void* l) {
    __builtin_amdgcn_global_load_lds((const __attribute__((address_space(1))) u32*)g,
                                     (__attribute__((address_space(3))) u32*)l, 16, 0, 0);
}

// -------- prep: 7 plain cvt segs + 2 transpose-cvt segs (y==7/8) + LayerNorm (y==9) --
struct CvtSeg { const float* s; bf16* d; int n; };
struct CvtArgs { CvtSeg seg[7]; const float* tsrc[2]; bf16* tdst[2]; };
__global__ __launch_bounds__(256) void prep_kernel(CvtArgs a,
                                                   const float* __restrict__ x,
                                                   const float* __restrict__ g,
                                                   const float* __restrict__ be,
                                                   bf16* __restrict__ xn) {
    if (blockIdx.y < 7) {
        CvtSeg sg = a.seg[blockIdx.y];
        int base = (blockIdx.x * 256 + threadIdx.x) * 4;
        if (base >= sg.n) return;
        float4 v = *(const float4*)(sg.s + base);
        ushort4 o;
        o.x = bfbits(v.x); o.y = bfbits(v.y); o.z = bfbits(v.z); o.w = bfbits(v.w);
        *(ushort4*)(sg.d + base) = o;
        return;
    }
    if (blockIdx.y < 9) {
        // tiled transpose-cvt: (DM x DI) fp32 -> (DI x DM) bf16, 64x64 tiles
        if (blockIdx.x >= (DM / 64) * (DI / 64)) return;
        const float* src = a.tsrc[blockIdx.y - 7];
        bf16* dst = a.tdst[blockIdx.y - 7];
        int tr = blockIdx.x >> 5;      // row tile 0..15 (DM/64)
        int tc = blockIdx.x & 31;      // col tile 0..31 (DI/64)
        __shared__ short ts[64][72];
        int t = threadIdx.x;
#pragma unroll
        for (int p = 0; p < 4; ++p) {
            int r = p * 16 + (t >> 4);
            int c = (t & 15) * 4;
            float4 v = *(const float4*)(src + (long)(tr * 64 + r) * DI + tc * 64 + c);
            ts[r][c + 0] = (short)bfbits(v.x);
            ts[r][c + 1] = (short)bfbits(v.y);
            ts[r][c + 2] = (short)bfbits(v.z);
            ts[r][c + 3] = (short)bfbits(v.w);
        }
        __syncthreads();
#pragma unroll
        for (int p = 0; p < 4; ++p) {
            int k2 = p * 16 + (t >> 4);   // transposed row within tile
            int j  = (t & 15) * 4;        // transposed col within tile
            ushort4 o;
            o.x = (unsigned short)ts[j + 0][k2];
            o.y = (unsigned short)ts[j + 1][k2];
            o.z = (unsigned short)ts[j + 2][k2];
            o.w = (unsigned short)ts[j + 3][k2];
            *(ushort4*)(dst + (long)(tc * 64 + k2) * DM + tr * 64 + j) = o;
        }
        return;
    }
    // LayerNorm over last dim (1024), bf16 out
    int row = blockIdx.x;
    const float* xr = x + (long)row * DM;
    float v[4];
    float s = 0.f, ss = 0.f;
#pragma unroll
    for (int i = 0; i < 4; ++i) {
        v[i] = xr[threadIdx.x + 256 * i];
        s += v[i]; ss += v[i] * v[i];
    }
#pragma unroll
    for (int off = 32; off >= 1; off >>= 1) {
        s  += __shfl_xor(s, off, 64);
        ss += __shfl_xor(ss, off, 64);
    }
    __shared__ float sh[8];
    int wid = threadIdx.x >> 6;
    if ((threadIdx.x & 63) == 0) { sh[wid] = s; sh[4 + wid] = ss; }
    __syncthreads();
    s  = sh[0] + sh[1] + sh[2] + sh[3];
    ss = sh[4] + sh[5] + sh[6] + sh[7];
    float mu  = s / DM;
    float var = ss / DM - mu * mu;
    float rs  = rsqrtf(var + 1e-5f);
    bf16* xo = xn + (long)row * DM;
#pragma unroll
    for (int i = 0; i < 4; ++i) {
        int c = threadIdx.x + 256 * i;
        xo[c] = __float2bfloat16((v[i] - mu) * rs * g[c] + be[c]);
    }
}

// ---------------- bf16 MFMA GEMM: BK=64, global_load_lds, 8-way XOR swizzle ---------
struct GPtr { const bf16* A; const bf16* B; void* C; void* X; };
struct GB8 { GPtr p[8]; };

// EPI: 0 plain store; 2 softplus(acc + X[col]); 3 +bias+resid
template <int EPI, typename OutT>
__global__ __launch_bounds__(256) void gemm_mfma(GB8 gb, int lda, int ldb, int ldc,
                                                 int N, int K,
                                                 const float* __restrict__ bias,
                                                 const float* __restrict__ resid, int ldr) {
    __shared__ __align__(16) short As[128 * 64];   // 16 KB
    __shared__ __align__(16) short Bs[128 * 64];   // 16 KB
    GPtr g = gb.p[blockIdx.z];
    const short* A = (const short*)g.A;
    const short* B = (const short*)g.B;
    OutT* C = (OutT*)g.C;
    const int tid = threadIdx.x;
    const int m0 = blockIdx.x * 128, n0 = blockIdx.y * 128;
    const int lane = tid & 63, wv = tid >> 6;
    const int wm = (wv >> 1) * 64, wn = (wv & 1) * 64;
    const int rsub = lane >> 3;
    const int sq   = ((lane & 7) ^ (rsub & 7)) * 8;   // swizzled 16B chunk (bf16 units)
    const short* pa[4];
    const short* pb[4];
    short* la[4];
    short* lb[4];
#pragma unroll
    for (int i = 0; i < 4; ++i) {
        int srow = wv * 32 + i * 8 + rsub;
        pa[i] = A + (long)(m0 + srow) * lda + sq;
        int rb = n0 + srow; rb = rb < N ? rb : N - 1;
        pb[i] = B + (long)rb * ldb + sq;
        la[i] = &As[(wv * 32 + i * 8) * 64];
        lb[i] = &Bs[(wv * 32 + i * 8) * 64];
    }
    f32x4 acc[4][4];
#pragma unroll
    for (int i = 0; i < 4; ++i)
#pragma unroll
        for (int j = 0; j < 4; ++j) acc[i][j] = (f32x4){0.f, 0.f, 0.f, 0.f};

    for (int k0 = 0; k0 < K; k0 += 64) {
        __syncthreads();
#pragma unroll
        for (int i = 0; i < 4; ++i) {
            async_cp16(pa[i] + k0, la[i]);
            async_cp16(pb[i] + k0, lb[i]);
        }
        __syncthreads();
#pragma unroll
        for (int h = 0; h < 2; ++h) {
            bf16x8 af[4], bfr[4];
#pragma unroll
            for (int t = 0; t < 4; ++t) {
                int ra = wm + t * 16 + (lane & 15);
                int ca = h * 4 + (lane >> 4);
                af[t]  = *(const bf16x8*)&As[ra * 64 + (ca ^ (ra & 7)) * 8];
                int rb = wn + t * 16 + (lane & 15);
                int cb = h * 4 + (lane >> 4);
                bfr[t] = *(const bf16x8*)&Bs[rb * 64 + (cb ^ (rb & 7)) * 8];
            }
#pragma unroll
            for (int i = 0; i < 4; ++i)
#pragma unroll
                for (int j = 0; j < 4; ++j)
                    acc[i][j] = __builtin_amdgcn_mfma_f32_16x16x32_bf16(af[i], bfr[j], acc[i][j], 0, 0, 0);
        }
    }
    float bcol[4] = {0.f, 0.f, 0.f, 0.f};
    if (EPI == 2 || EPI == 3) {
#pragma unroll
        for (int j = 0; j < 4; ++j) {
            int col = n0 + wn + j * 16 + (lane & 15);
            const float* bp = (EPI == 2) ? (const float*)g.X : bias;
            bcol[j] = (col < N) ? bp[col] : 0.f;
        }
    }
#pragma unroll
    for (int i = 0; i < 4; ++i) {
        int rowb = m0 + wm + i * 16 + ((lane >> 4) << 2);
#pragma unroll
        for (int j = 0; j < 4; ++j) {
            int col = n0 + wn + j * 16 + (lane & 15);
            if (col < N) {
#pragma unroll
                for (int rr = 0; rr < 4; ++rr) {
                    float v = acc[i][j][rr];
                    if (EPI == 3) v += bcol[j] + resid[(long)(rowb + rr) * ldr + col];
                    if (EPI == 2) v = softplus_f(v + bcol[j]);
                    stv(&C[(long)(rowb + rr) * ldc + col], v);
                }
            }
        }
    }
}

// ------- xred: sum 4 K-slices of x-proj partials -> dbl fp32 + dt bf16 dup ---------
__global__ __launch_bounds__(256) void xred_kernel(const float* __restrict__ xpart,
                                                   float* __restrict__ dbl,
                                                   bf16* __restrict__ dt_f,
                                                   bf16* __restrict__ dt_b) {
    int gid = blockIdx.x * 256 + threadIdx.x;   // 2*NTOK*24 threads
    const int per = NTOK * 24;
    int dir = gid >= per;
    int j = gid - dir * per;
    int row = j / 24;
    int c4 = (j - row * 24) * 4;
    long base = ((long)(dir * 4) * NTOK) * 96 + (long)row * 96 + c4;
    f32x4 s = *(const f32x4*)(xpart + base);
#pragma unroll
    for (int k = 1; k < 4; ++k) {
        f32x4 v = *(const f32x4*)(xpart + base + (long)k * NTOK * 96);
        s[0] += v[0]; s[1] += v[1]; s[2] += v[2]; s[3] += v[3];
    }
    *(f32x4*)(dbl + (long)dir * NTOK * 96 + (long)row * 96 + c4) = s;
    if (c4 < 64) {
        ushort4 o;
        o.x = bfbits(s[0]); o.y = bfbits(s[1]); o.z = bfbits(s[2]); o.w = bfbits(s[3]);
        *(ushort4*)((dir ? dt_b : dt_f) + (long)row * 64 + c4) = o;
    }
}

// ------- fred: out = fpart0 + fpart1 + fus_b + x  (final split-K reduce) -----------
__global__ __launch_bounds__(256) void fred_kernel(const float* __restrict__ fpart,
                                                   const float* __restrict__ bias,
                                                   const float* __restrict__ x,
                                                   float* __restrict__ out) {
    long i = ((long)blockIdx.x * 256 + threadIdx.x) * 4;    // < NTOK*DM
    int col = (int)(i & (DM - 1));
    f32x4 a  = *(const f32x4*)(fpart + i);
    f32x4 b  = *(const f32x4*)(fpart + (long)NTOK * DM + i);
    f32x4 bb = *(const f32x4*)(bias + col);
    f32x4 xv = *(const f32x4*)(x + i);
    f32x4 o;
#pragma unroll
    for (int k = 0; k < 4; ++k) o[k] = a[k] + b[k] + bb[k] + xv[k];
    *(f32x4*)(out + i) = o;
}

// ---------------- Depthwise causal conv (window 4) + SiLU, 8 channels/thread -------
__global__ __launch_bounds__(256) void conv_kernel(const bf16* __restrict__ xi_f,
                                                   const bf16* __restrict__ xi_b,
                                                   const float* __restrict__ wf,
                                                   const float* __restrict__ bfs,
                                                   const float* __restrict__ wb,
                                                   const float* __restrict__ bb,
                                                   bf16* __restrict__ xc_f,
                                                   bf16* __restrict__ xc_b) {
    long idx = (long)blockIdx.x * 256 + threadIdx.x;
    const long per = (long)NTOK * (DI / 8);
    int dir = idx >= per;
    long i  = dir ? idx - per : idx;
    int  d8 = (int)(i & 255) * 8;
    long tok = i >> 8;
    int  l  = (int)(tok & (SEQ - 1));
    const float* w    = dir ? wb : wf;
    const float* bias = dir ? bb : bfs;
    const bf16* xi = (dir ? xi_b : xi_f) + tok * DI + d8;
    float acc[8], wreg[8][4];
#pragma unroll
    for (int j = 0; j < 8; ++j) {
        acc[j] = bias[d8 + j];
        f32x4 wv = *(const f32x4*)(w + (d8 + j) * 4);
        wreg[j][0] = wv[0]; wreg[j][1] = wv[1]; wreg[j][2] = wv[2]; wreg[j][3] = wv[3];
    }
#pragma unroll
    for (int k = 0; k < 4; ++k) {
        int lp = dir ? (l + 3 - k) : (l - 3 + k);
        if (lp >= 0 && lp < SEQ) {
            bf16x8 v = *(const bf16x8*)(xi + (long)(lp - l) * DI);
#pragma unroll
            for (int j = 0; j < 8; ++j) acc[j] = fmaf(wreg[j][k], bf2f(v[j]), acc[j]);
        }
    }
    bf16x8 o;
#pragma unroll
    for (int j = 0; j < 8; ++j) o[j] = (short)bfbits(silu_f(acc[j]));
    *(bf16x8*)((dir ? xc_b : xc_f) + tok * DI + d8) = o;
}

// =========== Chunked selective scan: one lane owns one channel (16 states) ==========
__global__ __launch_bounds__(256) void scan_reduce(
        const bf16* __restrict__ delta_f, const bf16* __restrict__ delta_b,
        const bf16* __restrict__ xc_f, const bf16* __restrict__ xc_b,
        const float* __restrict__ dbl_f, const float* __restrict__ dbl_b,
        const float* __restrict__ Alog_f, const float* __restrict__ Alog_b,
        float* __restrict__ red_a, float* __restrict__ red_b) {
    int blk = blockIdx.x;
    int dg  = blk & 7;
    int c   = (blk >> 3) & 15;
    int b   = (blk >> 7) & 3;
    int dir = blk >> 9;
    int d   = dg * 256 + threadIdx.x;
    const bf16* delta = dir ? delta_b : delta_f;
    const bf16* xc    = dir ? xc_b : xc_f;
    const float* dbl  = dir ? dbl_b : dbl_f;
    const float* Alog = (dir ? Alog_b : Alog_f) + d * DS;
    __shared__ float Bsh[CLEN * 16];
    {
        int r = threadIdx.x >> 2, q = threadIdx.x & 3;
        long grow = (long)b * SEQ + (dir ? (SEQ - 1 - c * CLEN - r) : (c * CLEN + r));
        *(f32x4*)&Bsh[r * 16 + q * 4] = *(const f32x4*)(dbl + grow * 96 + 64 + q * 4);
    }
    __syncthreads();
    float Ar2[DS], aprod[DS], bacc[DS];
#pragma unroll
    for (int j = 0; j < DS; ++j) {
        Ar2[j] = -__expf(Alog[j]) * 1.44269504089f;
        aprod[j] = 1.f; bacc[j] = 0.f;
    }
    long tstep = dir ? -1 : 1;
    long row = (long)b * SEQ + (dir ? SEQ - 1 - c * CLEN : c * CLEN);
    float dlt = __bfloat162float(delta[row * DI + d]);
    float u   = __bfloat162float(xc[row * DI + d]);
    for (int s = 0; s < CLEN; ++s) {
        long rown = row + tstep;
        float dltn = 0.f, un = 0.f;
        if (s + 1 < CLEN) {
            dltn = __bfloat162float(delta[rown * DI + d]);
            un   = __bfloat162float(xc[rown * DI + d]);
        }
        float du = dlt * u;
#pragma unroll
        for (int q = 0; q < 4; ++q) {
            f32x4 Bq = *(const f32x4*)&Bsh[s * 16 + q * 4];
#pragma unroll
            for (int j = 0; j < 4; ++j) {
                int ix = q * 4 + j;
                float dA = fexp2(dlt * Ar2[ix]);
                bacc[ix]  = fmaf(bacc[ix], dA, du * Bq[j]);
                aprod[ix] *= dA;
            }
        }
        row = rown; dlt = dltn; u = un;
    }
    long base = (((long)(dir * 4 + b) * CHUNKS + c) * DI + d) * 16;
#pragma unroll
    for (int q = 0; q < 4; ++q) {
        *(f32x4*)(red_a + base + q * 4) =
            (f32x4){aprod[q*4], aprod[q*4+1], aprod[q*4+2], aprod[q*4+3]};
        *(f32x4*)(red_b + base + q * 4) =
            (f32x4){bacc[q*4], bacc[q*4+1], bacc[q*4+2], bacc[q*4+3]};
    }
}

__global__ __launch_bounds__(256) void scan_combine(float* __restrict__ red_a,
                                                    const float* __restrict__ red_b) {
    int tid = blockIdx.x * 256 + threadIdx.x;
    int sub = tid & 3;
    int d   = (tid >> 2) & 2047;
    int db  = tid >> 13;
    f32x4 h = (f32x4){0.f, 0.f, 0.f, 0.f};
    for (int c = 0; c < CHUNKS; ++c) {
        long idx = (((long)db * CHUNKS + c) * DI + d) * 16 + sub * 4;
        f32x4 a = *(const f32x4*)(red_a + idx);
        f32x4 w = *(const f32x4*)(red_b + idx);
        *(f32x4*)(red_a + idx) = h;
#pragma unroll
        for (int j = 0; j < 4; ++j) h[j] = fmaf(a[j], h[j], w[j]);
    }
}

// writes gated y into PACKED buffer y[tok][dir*DI + d] (ld 2*DI)
__global__ __launch_bounds__(256) void scan_apply(
        const bf16* __restrict__ delta_f, const bf16* __restrict__ delta_b,
        const bf16* __restrict__ xc_f, const bf16* __restrict__ xc_b,
        const bf16* __restrict__ z_f, const bf16* __restrict__ z_b,
        const float* __restrict__ dbl_f, const float* __restrict__ dbl_b,
        const float* __restrict__ Alog_f, const float* __restrict__ Alog_b,
        const float* __restrict__ Df, const float* __restrict__ Db,
        const float* __restrict__ red_a, bf16* __restrict__ ypack) {
    int blk = blockIdx.x;
    int dg  = blk & 7;
    int c   = (blk >> 3) & 15;
    int b   = (blk >> 7) & 3;
    int dir = blk >> 9;
    int d   = dg * 256 + threadIdx.x;
    const bf16* delta = dir ? delta_b : delta_f;
    const bf16* xc    = dir ? xc_b : xc_f;
    const bf16* z     = dir ? z_b : z_f;
    const float* dbl  = dir ? dbl_b : dbl_f;
    const float* Alog = (dir ? Alog_b : Alog_f) + d * DS;
    float Dd = (dir ? Db : Df)[d];
    bf16* yo = ypack + dir * DI + d;
    __shared__ float BCsh[CLEN * 32];
#pragma unroll
    for (int it = 0; it < 2; ++it) {
        int i = it * 256 + threadIdx.x;
        int r = i >> 3, q = i & 7;
        long grow = (long)b * SEQ + (dir ? (SEQ - 1 - c * CLEN - r) : (c * CLEN + r));
        *(f32x4*)&BCsh[r * 32 + q * 4] = *(const f32x4*)(dbl + grow * 96 + 64 + q * 4);
    }
    __syncthreads();
    float Ar2[DS], h[DS];
#pragma unroll
    for (int j = 0; j < DS; ++j) Ar2[j] = -__expf(Alog[j]) * 1.44269504089f;
    {
        long base = (((long)(dir * 4 + b) * CHUNKS + c) * DI + d) * 16;
#pragma unroll
        for (int q = 0; q < 4; ++q) {
            f32x4 h0 = *(const f32x4*)(red_a + base + q * 4);
            h[q*4] = h0[0]; h[q*4+1] = h0[1]; h[q*4+2] = h0[2]; h[q*4+3] = h0[3];
        }
    }
    long tstep = dir ? -1 : 1;
    long row = (long)b * SEQ + (dir ? SEQ - 1 - c * CLEN : c * CLEN);
    float dlt = __bfloat162float(delta[row * DI + d]);
    float u   = __bfloat162float(xc[row * DI + d]);
    float zg  = __bfloat162float(z[row * DI + d]);
    for (int s = 0; s < CLEN; ++s) {
        long rown = row + tstep;
        float dltn = 0.f, un = 0.f, zgn = 0.f;
        if (s + 1 < CLEN) {
            dltn = __bfloat162float(delta[rown * DI + d]);
            un   = __bfloat162float(xc[rown * DI + d]);
            zgn  = __bfloat162float(z[rown * DI + d]);
        }
        float du = dlt * u;
        float y = 0.f;
#pragma unroll
        for (int q = 0; q < 4; ++q) {
            f32x4 Bq = *(const f32x4*)&BCsh[s * 32 + q * 4];
            f32x4 Cq = *(const f32x4*)&BCsh[s * 32 + 16 + q * 4];
#pragma unroll
            for (int j = 0; j < 4; ++j) {
                int ix = q * 4 + j;
                float dA = fexp2(dlt * Ar2[ix]);
                h[ix] = fmaf(h[ix], dA, du * Bq[j]);
                y = fmaf(h[ix], Cq[j], y);
            }
        }
        float yv = fmaf(u, Dd, y);
        yo[row * (2 * DI)] = __float2bfloat16(yv * silu_f(zg));
        row = rown; dlt = dltn; u = un; zg = zgn;
    }
}

extern "C" void kernel_launch(void* const* d_in, const int* in_sizes, int n_in,
                              void* d_out, int out_size, void* d_ws, size_t ws_size,
                              hipStream_t stream) {
    const float* x      = (const float*)d_in[0];
    const float* ln_g   = (const float*)d_in[1];
    const float* ln_b   = (const float*)d_in[2];
    const float* fus_w  = (const float*)d_in[3];
    const float* fus_b  = (const float*)d_in[4];
    const float* f_in_w = (const float*)d_in[5];
    const float* f_cw   = (const float*)d_in[6];
    const float* f_cb   = (const float*)d_in[7];
    const float* f_xpw  = (const float*)d_in[8];
    const float* f_dtw  = (const float*)d_in[9];
    const float* f_dtb  = (const float*)d_in[10];
    const float* f_Alog = (const float*)d_in[11];
    const float* f_D    = (const float*)d_in[12];
    const float* f_outw = (const float*)d_in[13];
    const float* b_in_w = (const float*)d_in[14];
    const float* b_cw   = (const float*)d_in[15];
    const float* b_cb   = (const float*)d_in[16];
    const float* b_xpw  = (const float*)d_in[17];
    const float* b_dtw  = (const float*)d_in[18];
    const float* b_dtb  = (const float*)d_in[19];
    const float* b_Alog = (const float*)d_in[20];
    const float* b_D    = (const float*)d_in[21];
    const float* b_outw = (const float*)d_in[22];
    float* out = (float*)d_out;

    char* w = (char*)d_ws;
    auto alloc = [&](size_t bytes) { char* p = w; w += (bytes + 255) & ~255UL; return p; };
    bf16* xn   = (bf16*)alloc((size_t)NTOK * DM * 2);
    bf16* xi_f = (bf16*)alloc((size_t)NTOK * DI * 2);    // delta_f; later fpart slice 0
    bf16* xi_b = (bf16*)alloc((size_t)NTOK * DI * 2);    // delta_b; later fpart slice 1
    bf16* z_f  = (bf16*)alloc((size_t)NTOK * DI * 2);
    bf16* z_b  = (bf16*)alloc((size_t)NTOK * DI * 2);
    bf16* xc_f = (bf16*)alloc((size_t)NTOK * DI * 2);
    bf16* xc_b = (bf16*)alloc((size_t)NTOK * DI * 2);
    bf16* ypack = (bf16*)alloc((size_t)NTOK * 2 * DI * 2);  // 32 MB; xpart before scan
    float* dbl = (float*)alloc((size_t)2 * NTOK * 96 * 4);
    float* dbl_f = dbl;
    float* dbl_b = dbl + (size_t)NTOK * 96;
    bf16* dt_f  = (bf16*)alloc((size_t)NTOK * DTR * 2);
    bf16* dt_b  = (bf16*)alloc((size_t)NTOK * DTR * 2);
    bf16* w_fin  = (bf16*)alloc((size_t)2 * DI * DM * 2);
    bf16* w_bin  = (bf16*)alloc((size_t)2 * DI * DM * 2);
    bf16* w_foutT = (bf16*)alloc((size_t)DI * DM * 2);   // out_w^T (DI x DM)
    bf16* w_boutT = (bf16*)alloc((size_t)DI * DM * 2);
    bf16* w_fus  = (bf16*)alloc((size_t)DM * 2 * DM * 2);
    bf16* w_comb = (bf16*)alloc((size_t)DM * 2 * DI * 2);  // Wcomb (DM x 2*DI) = 8 MB
    bf16* w_fxp  = (bf16*)alloc((size_t)96 * DI * 2);
    bf16* w_bxp  = (bf16*)alloc((size_t)96 * DI * 2);
    bf16* w_fdt  = (bf16*)alloc((size_t)DI * DTR * 2);
    bf16* w_bdt  = (bf16*)alloc((size_t)DI * DTR * 2);
    float* red_a = (float*)alloc((size_t)8 * CHUNKS * DI * 16 * 4);
    float* red_b = (float*)alloc((size_t)8 * CHUNKS * DI * 16 * 4);
    bf16* delta_f = xi_f;          // alias: xi dead after conv
    bf16* delta_b = xi_b;
    float* xpart = (float*)ypack;  // alias: 8 x (NTOK*96) fp32 = 12.6 MB, dead before
                                   // scan_apply writes ypack
    float* fpart = (float*)xi_f;   // alias: 2 x (NTOK*DM) fp32 = 33.5 MB over xi_f+xi_b
                                   // (delta dead after scan_apply)

    // 1. weight cvt (+ out_w transposes) + LayerNorm (one launch)
    CvtArgs ca;
    ca.seg[0] = {f_in_w, w_fin,  2 * DI * DM};
    ca.seg[1] = {b_in_w, w_bin,  2 * DI * DM};
    ca.seg[2] = {fus_w,  w_fus,  DM * 2 * DM};
    ca.seg[3] = {f_xpw,  w_fxp,  96 * DI};
    ca.seg[4] = {b_xpw,  w_bxp,  96 * DI};
    ca.seg[5] = {f_dtw,  w_fdt,  DI * DTR};
    ca.seg[6] = {b_dtw,  w_bdt,  DI * DTR};
    ca.tsrc[0] = f_outw; ca.tdst[0] = w_foutT;
    ca.tsrc[1] = b_outw; ca.tdst[1] = w_boutT;
    prep_kernel<<<dim3(4096, 10), 256, 0, stream>>>(ca, x, ln_g, ln_b, xn);
    // 1b. Wcomb = [fus_L @ f_out_w | fus_R @ b_out_w]  (z=2, M=1024 N=2048 K=1024)
    {
        GB8 gb{};
        gb.p[0] = {w_fus,      w_foutT, w_comb,      nullptr};
        gb.p[1] = {w_fus + DM, w_boutT, w_comb + DI, nullptr};
        gemm_mfma<0, bf16><<<dim3(8, 16, 2), 256, 0, stream>>>(gb, 2 * DM, DM, 2 * DI,
                                                               DI, DM, nullptr, nullptr, 0);
    }
    // 2. in-proj (batched z=4)
    {
        GB8 gb{};
        gb.p[0] = {xn, w_fin,                   xi_f, nullptr};
        gb.p[1] = {xn, w_fin + (size_t)DI * DM, z_f,  nullptr};
        gb.p[2] = {xn, w_bin,                   xi_b, nullptr};
        gb.p[3] = {xn, w_bin + (size_t)DI * DM, z_b,  nullptr};
        gemm_mfma<0, bf16><<<dim3(32, 16, 4), 256, 0, stream>>>(gb, DM, DM, DI, DI, DM,
                                                                nullptr, nullptr, 0);
    }
    // 3. depthwise conv + silu (8 ch/thread)
    conv_kernel<<<2 * NTOK, 256, 0, stream>>>(xi_f, xi_b, f_cw, f_cb,
                                              b_cw, b_cb, xc_f, xc_b);
    // 4. x-proj K-split x4 into private partials (plain fp32 stores, no atomics)
    {
        GB8 gb{};
        for (int s = 0; s < 4; ++s) {
            gb.p[s]     = {xc_f + s * 512, w_fxp + s * 512,
                           xpart + (size_t)s * NTOK * 96, nullptr};
            gb.p[4 + s] = {xc_b + s * 512, w_bxp + s * 512,
                           xpart + (size_t)(4 + s) * NTOK * 96, nullptr};
        }
        gemm_mfma<0, float><<<dim3(32, 1, 8), 256, 0, stream>>>(gb, DI, DI, 96, 96, 512,
                                                                nullptr, nullptr, 0);
    }
    // 5. xred: sum slices -> dbl fp32 + dt bf16
    xred_kernel<<<2 * NTOK * 24 / 256, 256, 0, stream>>>(xpart, dbl, dt_f, dt_b);
    // 6. dt-proj + softplus -> bf16 delta (MFMA, K=64, z=2)
    {
        GB8 gb{};
        gb.p[0] = {dt_f, w_fdt, delta_f, (void*)f_dtb};
        gb.p[1] = {dt_b, w_bdt, delta_b, (void*)b_dtb};
        gemm_mfma<2, bf16><<<dim3(32, 16, 2), 256, 0, stream>>>(gb, DTR, DTR, DI, DI, DTR,
                                                                nullptr, nullptr, 0);
    }
    // 7. chunked selective scan (3 passes); apply writes packed y (over xpart region)
    scan_reduce<<<1024, 256, 0, stream>>>(delta_f, delta_b, xc_f, xc_b,
                                          dbl_f, dbl_b, f_Alog, b_Alog, red_a, red_b);
    scan_combine<<<256, 256, 0, stream>>>(red_a, red_b);
    scan_apply<<<1024, 256, 0, stream>>>(delta_f, delta_b, xc_f, xc_b, z_f, z_b,
                                         dbl_f, dbl_b, f_Alog, b_Alog, f_D, b_D,
                                         red_a, ypack);
    // 8. fused out-proj+fuse, K-split x2 into private partials (plain fp32 stores)
    //    (M=4096, N=1024, K=2048/slice); delta (xi) dead -> fpart aliases it
    {
        GB8 gb{};
        gb.p[0] = {ypack,      w_comb,      fpart,                    nullptr};
        gb.p[1] = {ypack + DI, w_comb + DI, fpart + (size_t)NTOK * DM, nullptr};
        gemm_mfma<0, float><<<dim3(32, 8, 2), 256, 0, stream>>>(gb, 2 * DI, 2 * DI, DM,
                                                                DM, DI, nullptr, nullptr, 0);
    }
    // 9. fred: out = fpart0 + fpart1 + fus_b + x
    fred_kernel<<<NTOK * DM / 4 / 256, 256, 0, stream>>>(fpart, fus_b, x, out);
}